// Round 4
// baseline (209.287 us; speedup 1.0000x reference)
//
#include <hip/hip_runtime.h>
#include <math.h>

// PinSAGE fused pipeline, persistent bf16-MFMA edition.
// D=U=E=128, T=20 fixed by the reference; N, V from in_sizes.
//
// K0 prep:   WqT/WnT/WwT/WgT = bf16 transpose of weights (WT[n][k])
// K1 dual:   H = relu(table @ Wn + bn) -> bf16 [V][128]        (blocks < splitH)
//            nodeh = relu(table[node_ids] @ Wq + bq) -> nh[:,0:128]  (rest)
//            persistent waves, W staged once/block, 16-row tiles,
//            one-tile-ahead register prefetch, no steady-state barriers.
// K2 agg:    nh[:,128:256] = sum_t alpha * H[neigh]            (gather-FMA)
// K3 emb:    embb = relu(nh @ Ww + bw) bf16 + per-block sumsq partials
// K4 final:  out = relu((1/||emb||)*(embb @ Wg) + bg) fp32; partials
//            reduced inline per block (no separate reduce kernel).
//
// MFMA orientation (verified r3): lane l of a wave holds C[row=tile*16+(l&15)]
// [cols 16*mt+4*(l>>4)+i] -> A-rows stream global->regs, C streams regs->global.

using f32x4  = __attribute__((ext_vector_type(4))) float;
using short8 = __attribute__((ext_vector_type(8))) short;   // 8 bf16

__device__ __forceinline__ ushort f2bf(float f) {
    uint u = __float_as_uint(f);
    return (ushort)((u + 0x7fffu + ((u >> 16) & 1u)) >> 16);   // RNE
}
__device__ __forceinline__ float bf2f(ushort h) {
    return __uint_as_float((uint)h << 16);
}
__device__ __forceinline__ uint pk2(float lo, float hi) {
    return (uint)f2bf(lo) | ((uint)f2bf(hi) << 16);
}
__device__ __forceinline__ short8 pack8(f32x4 a, f32x4 b) {
    uint4 r;
    r.x = pk2(a[0], a[1]); r.y = pk2(a[2], a[3]);
    r.z = pk2(b[0], b[1]); r.w = pk2(b[2], b[3]);
    union { uint4 u; short8 s; } cv; cv.u = r; return cv.s;
}

// ---------------------------------------------------------------------------
__global__ __launch_bounds__(256)
void prep_weights(const float* __restrict__ Wq, const float* __restrict__ Wn,
                  const float* __restrict__ Ww, const float* __restrict__ Wg,
                  ushort* __restrict__ WqT, ushort* __restrict__ WnT,
                  ushort* __restrict__ WwT, ushort* __restrict__ WgT)
{
    int idx = blockIdx.x * 256 + threadIdx.x;   // 320 blocks -> 81920
    const float* W; ushort* WT; int K; int j = idx;
    if (j < 16384)      { W = Wq; WT = WqT; K = 128; }
    else if (j < 32768) { W = Wn; WT = WnT; K = 128; j -= 16384; }
    else if (j < 65536) { W = Ww; WT = WwT; K = 256; j -= 32768; }
    else                { W = Wg; WT = WgT; K = 128; j -= 65536; }
    int n = j & 127, k = j >> 7;
    WT[(size_t)n * K + k] = f2bf(W[j]);
}

// ---------------------------------------------------------------------------
// K1: dual persistent fp32-input GEMM (H and nodeh share one launch).
// ---------------------------------------------------------------------------
__device__ __forceinline__ void stage_w128(const ushort* __restrict__ WT,
                                           const float* __restrict__ bias,
                                           ushort* Wlds, float* blds, int tid)
{
#pragma unroll
    for (int it = 0; it < 8; ++it) {
        int idx = it * 256 + tid, n = idx >> 4, o = idx & 15;
        uint4 v = *reinterpret_cast<const uint4*>(&WT[(size_t)n * 128 + 8 * o]);
        *reinterpret_cast<uint4*>((char*)Wlds + n * 256 + ((16 * o) ^ ((n & 7) << 4))) = v;
    }
    if (tid < 128) blds[tid] = bias[tid];
}

template<bool GATHER>
__device__ __forceinline__ void k1_loop(const float* __restrict__ table,
                                        const int* __restrict__ gidx,
                                        const ushort* Wlds, const float* blds,
                                        ushort* __restrict__ out, int ldo, int M,
                                        int wslot, int stride, int l16, int lh)
{
    const int nt = (M + 15) >> 4;
    int tile = wslot;
    if (tile >= nt) return;

    f32x4 t[8];
    {   // prologue: issue loads for first tile
        int row = tile * 16 + l16; int g = (row < M) ? row : (M - 1);
        if (GATHER) g = gidx[g];
        const float* rp = table + (size_t)g * 128 + 8 * lh;
#pragma unroll
        for (int ks = 0; ks < 4; ++ks) {
            t[2 * ks]     = *reinterpret_cast<const f32x4*>(rp + 32 * ks);
            t[2 * ks + 1] = *reinterpret_cast<const f32x4*>(rp + 32 * ks + 4);
        }
    }
    for (; tile < nt; tile += stride) {
        short8 a[4];                       // pack current (waits on t loads)
#pragma unroll
        for (int ks = 0; ks < 4; ++ks) a[ks] = pack8(t[2 * ks], t[2 * ks + 1]);

        const int nxt = tile + stride;     // prefetch next tile into t
        if (nxt < nt) {
            int row = nxt * 16 + l16; int g = (row < M) ? row : (M - 1);
            if (GATHER) g = gidx[g];
            const float* rp = table + (size_t)g * 128 + 8 * lh;
#pragma unroll
            for (int ks = 0; ks < 4; ++ks) {
                t[2 * ks]     = *reinterpret_cast<const f32x4*>(rp + 32 * ks);
                t[2 * ks + 1] = *reinterpret_cast<const f32x4*>(rp + 32 * ks + 4);
            }
        }

        f32x4 acc[8];
#pragma unroll
        for (int mt = 0; mt < 8; ++mt)
#pragma unroll
            for (int i = 0; i < 4; ++i) acc[mt][i] = 0.f;
#pragma unroll
        for (int ks = 0; ks < 4; ++ks)
#pragma unroll
            for (int mt = 0; mt < 8; ++mt) {
                short8 wf = *reinterpret_cast<const short8*>(
                    (const char*)Wlds + (16 * mt + l16) * 256 +
                    ((64 * ks + 16 * lh) ^ ((l16 & 7) << 4)));
                acc[mt] = __builtin_amdgcn_mfma_f32_16x16x32_bf16(wf, a[ks], acc[mt], 0, 0, 0);
            }

        const int row = tile * 16 + l16;
        if (row < M) {
#pragma unroll
            for (int mt = 0; mt < 8; ++mt) {
                f32x4 bv = *reinterpret_cast<const f32x4*>(&blds[16 * mt + 4 * lh]);
                uint2 p;
                p.x = pk2(fmaxf(acc[mt][0] + bv[0], 0.f), fmaxf(acc[mt][1] + bv[1], 0.f));
                p.y = pk2(fmaxf(acc[mt][2] + bv[2], 0.f), fmaxf(acc[mt][3] + bv[3], 0.f));
                *reinterpret_cast<uint2*>(&out[(size_t)row * ldo + 16 * mt + 4 * lh]) = p;
            }
        }
    }
}

__global__ __launch_bounds__(256, 4)
void k1_dual(const float* __restrict__ table, const int* __restrict__ node_ids,
             const ushort* __restrict__ WnT, const float* __restrict__ bn,
             const ushort* __restrict__ WqT, const float* __restrict__ bq,
             ushort* __restrict__ H, ushort* __restrict__ nh,
             int V, int N, int splitH)
{
    __shared__ __align__(16) ushort Wlds[128 * 128];   // 32 KB
    __shared__ __align__(16) float blds[128];
    const int tid = threadIdx.x;
    const bool isH = (int)blockIdx.x < splitH;

    stage_w128(isH ? WnT : WqT, isH ? bn : bq, Wlds, blds, tid);
    __syncthreads();

    const int w = tid >> 6, l = tid & 63, l16 = l & 15, lh = l >> 4;
    if (isH) {
        k1_loop<false>(table, nullptr, Wlds, blds, H, 128, V,
                       blockIdx.x * 4 + w, splitH * 4, l16, lh);
    } else {
        k1_loop<true>(table, node_ids, Wlds, blds, nh, 256, N,
                      (blockIdx.x - splitH) * 4 + w, (gridDim.x - splitH) * 4, l16, lh);
    }
}

// ---------------------------------------------------------------------------
// K2: agg[n][:] = sum_t alpha[n,t] * H[neigh_ids[n,t]][:]
// ---------------------------------------------------------------------------
__global__ __launch_bounds__(256)
void agg_bf16(const ushort* __restrict__ H,
              const int* __restrict__ nids,
              const float* __restrict__ alpha,
              ushort* __restrict__ outb,     // nh + 128, row stride 256
              int N)
{
    const int n   = blockIdx.x * 16 + (threadIdx.x >> 4);
    const int l16 = threadIdx.x & 15;
    if (n >= N) return;

    const int*   idp = &nids[n * 20];
    const float* alp = &alpha[n * 20];
    float a[8];
#pragma unroll
    for (int j = 0; j < 8; ++j) a[j] = 0.f;
#pragma unroll
    for (int t = 0; t < 20; ++t) {
        const int   id = idp[t];
        const float al = alp[t];
        uint4 h = *reinterpret_cast<const uint4*>(&H[(size_t)id * 128 + 8 * l16]);
        a[0] = fmaf(al, bf2f((ushort)(h.x & 0xffff)), a[0]);
        a[1] = fmaf(al, bf2f((ushort)(h.x >> 16)),    a[1]);
        a[2] = fmaf(al, bf2f((ushort)(h.y & 0xffff)), a[2]);
        a[3] = fmaf(al, bf2f((ushort)(h.y >> 16)),    a[3]);
        a[4] = fmaf(al, bf2f((ushort)(h.z & 0xffff)), a[4]);
        a[5] = fmaf(al, bf2f((ushort)(h.z >> 16)),    a[5]);
        a[6] = fmaf(al, bf2f((ushort)(h.w & 0xffff)), a[6]);
        a[7] = fmaf(al, bf2f((ushort)(h.w >> 16)),    a[7]);
    }
    uint4 p;
    p.x = pk2(a[0], a[1]); p.y = pk2(a[2], a[3]);
    p.z = pk2(a[4], a[5]); p.w = pk2(a[6], a[7]);
    *reinterpret_cast<uint4*>(&outb[(size_t)n * 256 + 8 * l16]) = p;
}

// ---------------------------------------------------------------------------
// K3: emb = relu(nh @ Ww + bw) -> bf16 embb; per-block sumsq -> partials.
// Persistent, K=256, W staged once (64 KB LDS).
// ---------------------------------------------------------------------------
__global__ __launch_bounds__(256, 2)
void k3_emb(const ushort* __restrict__ nh, const ushort* __restrict__ WwT,
            const float* __restrict__ bw, ushort* __restrict__ embb,
            float* __restrict__ partials, int N)
{
    __shared__ __align__(16) ushort Wlds[128 * 256];   // 64 KB
    __shared__ __align__(16) float blds[128];
    __shared__ float red[256];
    const int tid = threadIdx.x;
#pragma unroll
    for (int it = 0; it < 16; ++it) {
        int idx = it * 256 + tid, n = idx >> 5, o = idx & 31;
        uint4 v = *reinterpret_cast<const uint4*>(&WwT[(size_t)n * 256 + 8 * o]);
        *reinterpret_cast<uint4*>((char*)Wlds + n * 512 + ((16 * o) ^ ((n & 7) << 4))) = v;
    }
    if (tid < 128) blds[tid] = bw[tid];
    __syncthreads();

    const int w = tid >> 6, l = tid & 63, l16 = l & 15, lh = l >> 4;
    const int nt = (N + 15) >> 4, stride = gridDim.x * 4;
    float ssq = 0.f;

    for (int tile = blockIdx.x * 4 + w; tile < nt; tile += stride) {
        const int row = tile * 16 + l16;
        const int g = (row < N) ? row : (N - 1);
        const ushort* rp = nh + (size_t)g * 256 + 8 * lh;
        short8 a[8];
#pragma unroll
        for (int ks = 0; ks < 8; ++ks)
            a[ks] = *reinterpret_cast<const short8*>(rp + 32 * ks);

        f32x4 acc[8];
#pragma unroll
        for (int mt = 0; mt < 8; ++mt)
#pragma unroll
            for (int i = 0; i < 4; ++i) acc[mt][i] = 0.f;
#pragma unroll
        for (int ks = 0; ks < 8; ++ks)
#pragma unroll
            for (int mt = 0; mt < 8; ++mt) {
                short8 wf = *reinterpret_cast<const short8*>(
                    (const char*)Wlds + (16 * mt + l16) * 512 +
                    ((64 * ks + 16 * lh) ^ ((l16 & 7) << 4)));
                acc[mt] = __builtin_amdgcn_mfma_f32_16x16x32_bf16(wf, a[ks], acc[mt], 0, 0, 0);
            }

        if (row < N) {
#pragma unroll
            for (int mt = 0; mt < 8; ++mt) {
                f32x4 bv = *reinterpret_cast<const f32x4*>(&blds[16 * mt + 4 * lh]);
                f32x4 v;
#pragma unroll
                for (int i = 0; i < 4; ++i) {
                    v[i] = fmaxf(acc[mt][i] + bv[i], 0.f);
                    ssq += v[i] * v[i];
                }
                uint2 p; p.x = pk2(v[0], v[1]); p.y = pk2(v[2], v[3]);
                *reinterpret_cast<uint2*>(&embb[(size_t)row * 128 + 16 * mt + 4 * lh]) = p;
            }
        }
    }

    red[tid] = ssq;
    __syncthreads();
    for (int st = 128; st > 0; st >>= 1) {
        if (tid < st) red[tid] += red[tid + st];
        __syncthreads();
    }
    if (tid == 0) partials[blockIdx.x] = red[0];
}

// ---------------------------------------------------------------------------
// K4: out = relu(scale*(embb @ Wg) + bg) fp32; scale reduced inline from
// partials[0..P). Persistent, K=128.
// ---------------------------------------------------------------------------
__global__ __launch_bounds__(256, 4)
void k4_final(const ushort* __restrict__ embb, const ushort* __restrict__ WgT,
              const float* __restrict__ bg, const float* __restrict__ partials,
              int P, float* __restrict__ outp, int N)
{
    __shared__ __align__(16) ushort Wlds[128 * 128];
    __shared__ __align__(16) float blds[128];
    __shared__ float red[256];
    __shared__ float s_scale;
    const int tid = threadIdx.x;

    stage_w128(WgT, bg, Wlds, blds, tid);
    float s = 0.f;
    for (int i = tid; i < P; i += 256) s += partials[i];
    red[tid] = s;
    __syncthreads();
    for (int st = 128; st > 0; st >>= 1) {
        if (tid < st) red[tid] += red[tid + st];
        __syncthreads();
    }
    if (tid == 0) s_scale = 1.0f / sqrtf(red[0]);
    __syncthreads();
    const float scale = s_scale;

    const int w = tid >> 6, l = tid & 63, l16 = l & 15, lh = l >> 4;
    const int nt = (N + 15) >> 4, stride = gridDim.x * 4;

    for (int tile = blockIdx.x * 4 + w; tile < nt; tile += stride) {
        const int row = tile * 16 + l16;
        const int g = (row < N) ? row : (N - 1);
        const ushort* rp = embb + (size_t)g * 128 + 8 * lh;
        short8 a[4];
#pragma unroll
        for (int ks = 0; ks < 4; ++ks)
            a[ks] = *reinterpret_cast<const short8*>(rp + 32 * ks);

        f32x4 acc[8];
#pragma unroll
        for (int mt = 0; mt < 8; ++mt)
#pragma unroll
            for (int i = 0; i < 4; ++i) acc[mt][i] = 0.f;
#pragma unroll
        for (int ks = 0; ks < 4; ++ks)
#pragma unroll
            for (int mt = 0; mt < 8; ++mt) {
                short8 wf = *reinterpret_cast<const short8*>(
                    (const char*)Wlds + (16 * mt + l16) * 256 +
                    ((64 * ks + 16 * lh) ^ ((l16 & 7) << 4)));
                acc[mt] = __builtin_amdgcn_mfma_f32_16x16x32_bf16(wf, a[ks], acc[mt], 0, 0, 0);
            }

        if (row < N) {
#pragma unroll
            for (int mt = 0; mt < 8; ++mt) {
                f32x4 bv = *reinterpret_cast<const f32x4*>(&blds[16 * mt + 4 * lh]);
                f32x4 v;
#pragma unroll
                for (int i = 0; i < 4; ++i)
                    v[i] = fmaxf(fmaf(acc[mt][i], scale, bv[i]), 0.f);
                *reinterpret_cast<f32x4*>(&outp[(size_t)row * 128 + 16 * mt + 4 * lh]) = v;
            }
        }
    }
}

// ---------------------------------------------------------------------------
extern "C" void kernel_launch(void* const* d_in, const int* in_sizes, int n_in,
                              void* d_out, int out_size, void* d_ws, size_t ws_size,
                              hipStream_t stream)
{
    const int*   node_ids  = (const int*)  d_in[0];
    const int*   neigh_ids = (const int*)  d_in[1];
    const float* alpha     = (const float*)d_in[2];
    const float* table     = (const float*)d_in[3];
    const float* Wq        = (const float*)d_in[4];
    const float* bq        = (const float*)d_in[5];
    const float* Wn        = (const float*)d_in[6];
    const float* bn        = (const float*)d_in[7];
    const float* Ww        = (const float*)d_in[8];
    const float* bw        = (const float*)d_in[9];
    const float* Wg        = (const float*)d_in[10];
    const float* bg        = (const float*)d_in[11];

    const int N = in_sizes[0];            // 50000
    const int V = in_sizes[3] / 128;      // 200000
    float* out = (float*)d_out;

    // workspace layout
    ushort* H    = (ushort*)d_ws;                 // [V][128] bf16
    ushort* nh   = H    + (size_t)V * 128;        // [N][256] = [node_h | agg]
    ushort* embb = nh   + (size_t)N * 256;        // [N][128]
    ushort* WqT  = embb + (size_t)N * 128;
    ushort* WnT  = WqT  + 16384;
    ushort* WwT  = WnT  + 16384;
    ushort* WgT  = WwT  + 32768;
    float*  partials = (float*)(WgT + 16384);     // 512
    float*  scale    = partials + 512;

    const size_t need = (size_t)((char*)(scale + 16) - (char*)d_ws);
    if (ws_size < need) return;

    const int G1 = 1024;
    const long long tH = (V + 15) / 16, tN = (N + 15) / 16;
    int splitH = (int)((G1 * tH) / (tH + tN));
    if (splitH < 1) splitH = 1;
    if (splitH > G1 - 1) splitH = G1 - 1;
    const int G3 = 512, G4 = 512;

    prep_weights<<<320, 256, 0, stream>>>(Wq, Wn, Ww, Wg, WqT, WnT, WwT, WgT);
    k1_dual<<<G1, 256, 0, stream>>>(table, node_ids, WnT, bn, WqT, bq,
                                    H, nh, V, N, splitH);
    agg_bf16<<<(N + 15) / 16, 256, 0, stream>>>(H, neigh_ids, alpha, nh + 128, N);
    k3_emb<<<G3, 256, 0, stream>>>(nh, WwT, bw, embb, partials, N);
    k4_final<<<G4, 256, 0, stream>>>(embb, WgT, bg, partials, G3, out, N);
}

// Round 5
// 103.750 us; speedup vs baseline: 2.0172x; 2.0172x over previous
//
#include <hip/hip_runtime.h>
#include <math.h>

// PinSAGE fused pipeline, r5: persistent contiguous-load K1 + r2 baseline rest.
// D=U=E=128, T=20 fixed; N, V from in_sizes.
//
// K0 prep:    WqT/WnT/WwT/WgT = bf16 transpose of weights (WT[n][k])
// K1 dual:    H = relu(table @ Wn + bn) -> bf16 [V][128]   (blocks < splitH)
//             nodeh = relu(table[node_ids] @ Wq + bq) -> nh[:,0:128] (rest)
//             persistent; 64-row tiles; contiguous global loads -> regs ->
//             bf16 LDS bounce; prefetch never crosses a barrier.
// K2 agg:     nh[:,128:256] = sum_t alpha * H[neigh]       (gather-FMA)
// K3 emb:     embb = relu(nh @ Ww + bw) bf16 + sumsq partials   (r2 kernel)
// K4 norm:    scale = 1/||emb||_F
// K5 final:   out = relu(scale*(embb @ Wg) + bg) fp32           (r2 kernel)

using f32x4  = __attribute__((ext_vector_type(4))) float;
using short8 = __attribute__((ext_vector_type(8))) short;   // 8 bf16

__device__ __forceinline__ ushort f2bf(float f) {
    uint u = __float_as_uint(f);
    return (ushort)((u + 0x7fffu + ((u >> 16) & 1u)) >> 16);   // RNE
}
__device__ __forceinline__ float bf2f(ushort h) {
    return __uint_as_float((uint)h << 16);
}
__device__ __forceinline__ uint pk2(float lo, float hi) {
    return (uint)f2bf(lo) | ((uint)f2bf(hi) << 16);
}

// ---------------------------------------------------------------------------
__global__ __launch_bounds__(256)
void prep_weights(const float* __restrict__ Wq, const float* __restrict__ Wn,
                  const float* __restrict__ Ww, const float* __restrict__ Wg,
                  ushort* __restrict__ WqT, ushort* __restrict__ WnT,
                  ushort* __restrict__ WwT, ushort* __restrict__ WgT)
{
    int idx = blockIdx.x * 256 + threadIdx.x;   // 320 blocks -> 81920
    const float* W; ushort* WT; int K; int j = idx;
    if (j < 16384)      { W = Wq; WT = WqT; K = 128; }
    else if (j < 32768) { W = Wn; WT = WnT; K = 128; j -= 16384; }
    else if (j < 65536) { W = Ww; WT = WwT; K = 256; j -= 32768; }
    else                { W = Wg; WT = WgT; K = 128; j -= 65536; }
    int n = j & 127, k = j >> 7;
    WT[(size_t)n * K + k] = f2bf(W[j]);
}

// ---------------------------------------------------------------------------
// K1: persistent dual GEMM (H-stream + node gather in one launch).
// LDS: W 32 KB (once) + A-tile 16 KB (64 rows bf16, swizzled) -> 3 blocks/CU.
// Per iter: pack(regs) -> sync -> ds_write -> sync -> prefetch next ->
//           MFMA -> store. Prefetch loads never cross a barrier.
// ---------------------------------------------------------------------------
__device__ __forceinline__ void stage_w128(const ushort* __restrict__ WT,
                                           const float* __restrict__ bias,
                                           ushort* Wlds, float* blds, int tid)
{
#pragma unroll
    for (int it = 0; it < 8; ++it) {
        int idx = it * 256 + tid, n = idx >> 4, o = idx & 15;
        uint4 v = *reinterpret_cast<const uint4*>(&WT[(size_t)n * 128 + 8 * o]);
        *reinterpret_cast<uint4*>((char*)Wlds + n * 256 + ((16 * o) ^ ((n & 7) << 4))) = v;
    }
    if (tid < 128) blds[tid] = bias[tid];
}

template<bool GATHER>
__device__ __forceinline__ void k1_side(const float* __restrict__ table,
                                        const int* __restrict__ gidx,
                                        const ushort* Wlds, const float* blds,
                                        ushort* Albs,
                                        ushort* __restrict__ out, int ldo, int M,
                                        int sideIdx, int sideBlk)
{
    const int tid = threadIdx.x;
    const int w = tid >> 6, l = tid & 63, l16 = l & 15, lh = l >> 4;
    const int nt = (M + 63) >> 6;
    int tile = sideIdx;

    f32x4 f[8];
    // prologue: issue loads for first tile (contiguous: wave covers 1 KB/instr)
    if (tile < nt) {
#pragma unroll
        for (int j = 0; j < 8; ++j) {
            int u = j * 256 + tid;           // float4 unit within 64x128 tile
            int r = u >> 5, c4 = u & 31;
            int row = tile * 64 + r;
            int g = (row < M) ? row : (M - 1);
            if (GATHER) g = gidx[g];
            f[j] = *reinterpret_cast<const f32x4*>(table + (size_t)g * 128 + 4 * c4);
        }
    }
    __syncthreads();   // W-stage visible (also drains prologue loads; fine)

    for (; tile < nt; tile += sideBlk) {
        // ---- pack current tile (waits the f loads) ----
        uint2 p[8];
#pragma unroll
        for (int j = 0; j < 8; ++j) {
            p[j].x = pk2(f[j][0], f[j][1]);
            p[j].y = pk2(f[j][2], f[j][3]);
        }
        __syncthreads();   // b1: all waves' MFMA reads of Albs done
#pragma unroll
        for (int j = 0; j < 8; ++j) {
            int u = j * 256 + tid, r = u >> 5, c4 = u & 31;
            *reinterpret_cast<uint2*>(
                (char*)Albs + r * 256 + ((8 * c4) ^ ((r & 7) << 4))) = p[j];
        }
        __syncthreads();   // b2: writes visible (lgkm only; no vmem in flight)

        // ---- prefetch next tile (issued after b2, consumed before next b1) ----
        const int nxt = tile + sideBlk;
        if (nxt < nt) {
#pragma unroll
            for (int j = 0; j < 8; ++j) {
                int u = j * 256 + tid;
                int r = u >> 5, c4 = u & 31;
                int row = nxt * 64 + r;
                int g = (row < M) ? row : (M - 1);
                if (GATHER) g = gidx[g];
                f[j] = *reinterpret_cast<const f32x4*>(table + (size_t)g * 128 + 4 * c4);
            }
        }

        // ---- MFMA: wave w owns rows 16w..16w+15 of the 64-row tile ----
        f32x4 acc[8];
#pragma unroll
        for (int mt = 0; mt < 8; ++mt)
#pragma unroll
            for (int i = 0; i < 4; ++i) acc[mt][i] = 0.f;
        const int r0 = 16 * w + l16;
#pragma unroll
        for (int ks = 0; ks < 4; ++ks) {
            short8 a = *reinterpret_cast<const short8*>(
                (const char*)Albs + r0 * 256 + ((64 * ks + 16 * lh) ^ ((r0 & 7) << 4)));
#pragma unroll
            for (int mt = 0; mt < 8; ++mt) {
                short8 wf = *reinterpret_cast<const short8*>(
                    (const char*)Wlds + (16 * mt + l16) * 256 +
                    ((64 * ks + 16 * lh) ^ ((l16 & 7) << 4)));
                acc[mt] = __builtin_amdgcn_mfma_f32_16x16x32_bf16(wf, a, acc[mt], 0, 0, 0);
            }
        }

        // ---- epilogue: bias+relu, bf16 direct store ----
        const int row = tile * 64 + r0;
        if (row < M) {
#pragma unroll
            for (int mt = 0; mt < 8; ++mt) {
                f32x4 bv = *reinterpret_cast<const f32x4*>(&blds[16 * mt + 4 * lh]);
                uint2 q;
                q.x = pk2(fmaxf(acc[mt][0] + bv[0], 0.f), fmaxf(acc[mt][1] + bv[1], 0.f));
                q.y = pk2(fmaxf(acc[mt][2] + bv[2], 0.f), fmaxf(acc[mt][3] + bv[3], 0.f));
                *reinterpret_cast<uint2*>(&out[(size_t)row * ldo + 16 * mt + 4 * lh]) = q;
            }
        }
    }
}

__global__ __launch_bounds__(256, 3)
void k1_dual(const float* __restrict__ table, const int* __restrict__ node_ids,
             const ushort* __restrict__ WnT, const float* __restrict__ bn,
             const ushort* __restrict__ WqT, const float* __restrict__ bq,
             ushort* __restrict__ H, ushort* __restrict__ nh,
             int V, int N, int splitH, int nBlk)
{
    __shared__ __align__(16) ushort Wlds[128 * 128];   // 32 KB
    __shared__ __align__(16) ushort Albs[64 * 128];    // 16 KB
    __shared__ __align__(16) float blds[128];
    const int tid = threadIdx.x;
    const bool isH = (int)blockIdx.x < splitH;

    stage_w128(isH ? WnT : WqT, isH ? bn : bq, Wlds, blds, tid);
    // barrier happens inside k1_side prologue

    if (isH)
        k1_side<false>(table, nullptr, Wlds, blds, Albs, H, 128, V,
                       blockIdx.x, splitH);
    else
        k1_side<true>(table, node_ids, Wlds, blds, Albs, nh, 256, N,
                      blockIdx.x - splitH, nBlk - splitH);
}

// ---------------------------------------------------------------------------
// K2: agg[n][:] = sum_t alpha[n,t] * H[neigh_ids[n,t]][:]
// ---------------------------------------------------------------------------
__global__ __launch_bounds__(256)
void agg_bf16(const ushort* __restrict__ H,
              const int* __restrict__ nids,
              const float* __restrict__ alpha,
              ushort* __restrict__ outb,     // nh + 128, row stride 256
              int N)
{
    const int n   = blockIdx.x * 16 + (threadIdx.x >> 4);
    const int l16 = threadIdx.x & 15;
    if (n >= N) return;

    const int*   idp = &nids[n * 20];
    const float* alp = &alpha[n * 20];
    float a[8];
#pragma unroll
    for (int j = 0; j < 8; ++j) a[j] = 0.f;
#pragma unroll
    for (int t = 0; t < 20; ++t) {
        const int   id = idp[t];
        const float al = alp[t];
        uint4 h = *reinterpret_cast<const uint4*>(&H[(size_t)id * 128 + 8 * l16]);
        a[0] = fmaf(al, bf2f((ushort)(h.x & 0xffff)), a[0]);
        a[1] = fmaf(al, bf2f((ushort)(h.x >> 16)),    a[1]);
        a[2] = fmaf(al, bf2f((ushort)(h.y & 0xffff)), a[2]);
        a[3] = fmaf(al, bf2f((ushort)(h.y >> 16)),    a[3]);
        a[4] = fmaf(al, bf2f((ushort)(h.z & 0xffff)), a[4]);
        a[5] = fmaf(al, bf2f((ushort)(h.z >> 16)),    a[5]);
        a[6] = fmaf(al, bf2f((ushort)(h.w & 0xffff)), a[6]);
        a[7] = fmaf(al, bf2f((ushort)(h.w >> 16)),    a[7]);
    }
    uint4 p;
    p.x = pk2(a[0], a[1]); p.y = pk2(a[2], a[3]);
    p.z = pk2(a[4], a[5]); p.w = pk2(a[6], a[7]);
    *reinterpret_cast<uint4*>(&outb[(size_t)n * 256 + 8 * l16]) = p;
}

// ---------------------------------------------------------------------------
// r2 LDS-staged MFMA GEMM (proven) — used for K3 (emb) and K5 (final).
// ---------------------------------------------------------------------------
template<int KTOT, bool GATHER, bool ABF16, bool SUMSQ, bool SCALE, bool OUTBF16>
__global__ __launch_bounds__(256, 2)
void mfma_gemm(const void* __restrict__ Av, int lda,
               const int* __restrict__ gidx,
               const ushort* __restrict__ WT,   // [128][KTOT] bf16 pre-transposed
               const float* __restrict__ bias,
               void* __restrict__ outv, int ldo, int M,
               float* __restrict__ partials,
               const float* __restrict__ scale_ptr)
{
    __shared__ __align__(16) char smem[65536];  // A: [0,32K)  B: [32K,64K)
    __shared__ float red[256];
    char* Bbase = smem + 32768;

    const int tid = threadIdx.x;
    const int w   = tid >> 6;
    const int l   = tid & 63;
    const int l16 = l & 15, lh = l >> 4;
    const int brow = blockIdx.x * 128;

    f32x4 acc[2][8];
#pragma unroll
    for (int fr = 0; fr < 2; ++fr)
#pragma unroll
        for (int fc = 0; fc < 8; ++fc)
#pragma unroll
            for (int i = 0; i < 4; ++i) acc[fr][fc][i] = 0.f;

    for (int k0 = 0; k0 < KTOT; k0 += 128) {
        if (ABF16) {
            const ushort* A = (const ushort*)Av;
#pragma unroll
            for (int it = 0; it < 8; ++it) {
                int idx = it * 256 + tid;
                int r = idx >> 4, o = idx & 15;
                int row = brow + r; int grow = (row < M) ? row : (M - 1);
                if (GATHER) grow = gidx[grow];
                uint4 v = *reinterpret_cast<const uint4*>(&A[(size_t)grow * lda + k0 + 8 * o]);
                *reinterpret_cast<uint4*>(smem + r * 256 + ((16 * o) ^ ((r & 7) << 4))) = v;
            }
        } else {
            const float* A = (const float*)Av;
#pragma unroll
            for (int it = 0; it < 16; ++it) {
                int idx = it * 256 + tid;
                int r = idx >> 5, q = idx & 31;
                int row = brow + r; int grow = (row < M) ? row : (M - 1);
                if (GATHER) grow = gidx[grow];
                float4 v = *reinterpret_cast<const float4*>(&A[(size_t)grow * lda + k0 + 4 * q]);
                uint2 p;
                p.x = pk2(v.x, v.y);
                p.y = pk2(v.z, v.w);
                *reinterpret_cast<uint2*>(smem + r * 256 + ((8 * q) ^ ((r & 7) << 4))) = p;
            }
        }
#pragma unroll
        for (int it = 0; it < 8; ++it) {
            int idx = it * 256 + tid;
            int n = idx >> 4, o = idx & 15;
            uint4 v = *reinterpret_cast<const uint4*>(&WT[(size_t)n * KTOT + k0 + 8 * o]);
            *reinterpret_cast<uint4*>(Bbase + n * 256 + ((16 * o) ^ ((n & 7) << 4))) = v;
        }
        __syncthreads();

        const int r0 = 32 * w + l16;
        const int r1 = r0 + 16;
#pragma unroll
        for (int ks = 0; ks < 4; ++ks) {
            const int kb = 64 * ks + 16 * lh;
            short8 a0 = *reinterpret_cast<const short8*>(
                smem + r0 * 256 + (kb ^ ((r0 & 7) << 4)));
            short8 a1 = *reinterpret_cast<const short8*>(
                smem + r1 * 256 + (kb ^ ((r1 & 7) << 4)));
#pragma unroll
            for (int fc = 0; fc < 8; ++fc) {
                const int nn = 16 * fc + l16;
                short8 b = *reinterpret_cast<const short8*>(
                    Bbase + nn * 256 + (kb ^ ((nn & 7) << 4)));
                acc[0][fc] = __builtin_amdgcn_mfma_f32_16x16x32_bf16(a0, b, acc[0][fc], 0, 0, 0);
                acc[1][fc] = __builtin_amdgcn_mfma_f32_16x16x32_bf16(a1, b, acc[1][fc], 0, 0, 0);
            }
        }
        __syncthreads();
    }

    const float scale = SCALE ? scale_ptr[0] : 1.0f;
    float bloc[8];
#pragma unroll
    for (int fc = 0; fc < 8; ++fc) bloc[fc] = bias[16 * fc + l16];

    float ssq = 0.f;
#pragma unroll
    for (int fr = 0; fr < 2; ++fr)
#pragma unroll
        for (int fc = 0; fc < 8; ++fc)
#pragma unroll
            for (int i = 0; i < 4; ++i) {
                const int r   = 32 * w + 16 * fr + 4 * lh + i;
                const int col = 16 * fc + l16;
                float v = fmaxf(fmaf(acc[fr][fc][i], scale, bloc[fc]), 0.f);
                if (SUMSQ) { if (brow + r < M) ssq += v * v; }
                if (OUTBF16) ((ushort*)smem)[r * 128 + col] = f2bf(v);
                else         ((float*)smem)[r * 128 + col] = v;
            }
    __syncthreads();

    if (OUTBF16) {
        ushort* out = (ushort*)outv;
#pragma unroll
        for (int it = 0; it < 8; ++it) {
            int idx = it * 256 + tid;
            int r = idx >> 4, o = idx & 15;
            if (brow + r < M)
                *reinterpret_cast<uint4*>(&out[(size_t)(brow + r) * ldo + 8 * o]) =
                    *reinterpret_cast<const uint4*>((ushort*)smem + r * 128 + 8 * o);
        }
    } else {
        float* out = (float*)outv;
#pragma unroll
        for (int it = 0; it < 16; ++it) {
            int idx = it * 256 + tid;
            int r = idx >> 5, q = idx & 31;
            if (brow + r < M)
                *reinterpret_cast<float4*>(&out[(size_t)(brow + r) * ldo + 4 * q]) =
                    *reinterpret_cast<const float4*>((float*)smem + r * 128 + 4 * q);
        }
    }

    if (SUMSQ) {
        red[tid] = ssq;
        __syncthreads();
        for (int st = 128; st > 0; st >>= 1) {
            if (tid < st) red[tid] += red[tid + st];
            __syncthreads();
        }
        if (tid == 0) partials[blockIdx.x] = red[0];
    }
}

// ---------------------------------------------------------------------------
__global__ void reduce_norm(const float* __restrict__ partials, int n,
                            float* __restrict__ scale)
{
    __shared__ float red[256];
    float s = 0.f;
    for (int i = threadIdx.x; i < n; i += 256) s += partials[i];
    red[threadIdx.x] = s;
    __syncthreads();
    for (int st = 128; st > 0; st >>= 1) {
        if (threadIdx.x < st) red[threadIdx.x] += red[threadIdx.x + st];
        __syncthreads();
    }
    if (threadIdx.x == 0) scale[0] = 1.0f / sqrtf(red[0]);
}

// ---------------------------------------------------------------------------
extern "C" void kernel_launch(void* const* d_in, const int* in_sizes, int n_in,
                              void* d_out, int out_size, void* d_ws, size_t ws_size,
                              hipStream_t stream)
{
    const int*   node_ids  = (const int*)  d_in[0];
    const int*   neigh_ids = (const int*)  d_in[1];
    const float* alpha     = (const float*)d_in[2];
    const float* table     = (const float*)d_in[3];
    const float* Wq        = (const float*)d_in[4];
    const float* bq        = (const float*)d_in[5];
    const float* Wn        = (const float*)d_in[6];
    const float* bn        = (const float*)d_in[7];
    const float* Ww        = (const float*)d_in[8];
    const float* bw        = (const float*)d_in[9];
    const float* Wg        = (const float*)d_in[10];
    const float* bg        = (const float*)d_in[11];

    const int N = in_sizes[0];            // 50000
    const int V = in_sizes[3] / 128;      // 200000
    float* out = (float*)d_out;

    // workspace layout
    ushort* H    = (ushort*)d_ws;                 // [V][128] bf16
    ushort* nh   = H    + (size_t)V * 128;        // [N][256] = [node_h | agg]
    ushort* embb = nh   + (size_t)N * 256;        // [N][128]
    ushort* WqT  = embb + (size_t)N * 128;
    ushort* WnT  = WqT  + 16384;
    ushort* WwT  = WnT  + 16384;
    ushort* WgT  = WwT  + 32768;
    float*  partials = (float*)(WgT + 16384);     // 512
    float*  scale    = partials + 512;

    const size_t need = (size_t)((char*)(scale + 16) - (char*)d_ws);
    if (ws_size < need) return;

    const int nblkN = (N + 127) / 128;

    // K1 grid: 768 persistent blocks (3/CU), split by tile counts
    const int G1 = 768;
    const long long tH = (V + 63) / 64, tN = (N + 63) / 64;
    int splitH = (int)((G1 * tH) / (tH + tN));
    if (splitH < 1) splitH = 1;
    if (splitH > G1 - 1) splitH = G1 - 1;

    prep_weights<<<320, 256, 0, stream>>>(Wq, Wn, Ww, Wg, WqT, WnT, WwT, WgT);
    k1_dual<<<G1, 256, 0, stream>>>(table, node_ids, WnT, bn, WqT, bq,
                                    H, nh, V, N, splitH, G1);
    agg_bf16<<<(N + 15) / 16, 256, 0, stream>>>(H, neigh_ids, alpha, nh + 128, N);
    mfma_gemm<256, false, true, true, false, true><<<nblkN, 256, 0, stream>>>(
        nh, 256, nullptr, WwT, bw, embb, 128, N, partials, nullptr);
    reduce_norm<<<1, 256, 0, stream>>>(partials, nblkN, scale);
    mfma_gemm<128, false, true, false, true, false><<<nblkN, 256, 0, stream>>>(
        embb, 128, nullptr, WgT, bg, out, 128, N, nullptr, scale);
}